// Round 2
// baseline (4583.321 us; speedup 1.0000x reference)
//
#include <hip/hip_runtime.h>
#include <hip/hip_bf16.h>

// Problem constants: inputs [T,B,D], state [B,H], W_xh [D,H], W_hh [H,H], b_h [H]
#define T_STEPS 256
#define B_SZ    64
#define D_SZ    1024
#define H_SZ    2048

// fp16 everywhere (2^-11 rounding vs bf16's 2^-9). Weights stored x256 so all
// entries are fp16-normal (W ~ U(0,0.01); 0.6% would be denormal unscaled);
// accumulator scaled by 1/256 in epilogue.
#define W_SCALE     256.0f
#define W_INV_SCALE 0.00390625f

typedef __attribute__((ext_vector_type(8))) _Float16 f16x8;  // 8 fp16 (4 VGPRs)
typedef __attribute__((ext_vector_type(4))) float    f32x4;  // MFMA 16x16 accumulator

// ---------------- conversion kernels ----------------

__global__ void cvt_f32_f16(const float* __restrict__ in,
                            _Float16* __restrict__ out, int n, float scale) {
    int i = blockIdx.x * blockDim.x + threadIdx.x;
    if (i < n) out[i] = (_Float16)(in[i] * scale);
}

// in[rows][cols] (fp32) -> out[cols][rows] (fp16, scaled). cols = 1<<log2cols.
__global__ void transpose_to_f16(const float* __restrict__ in,
                                 _Float16* __restrict__ out,
                                 int rows, int log2cols, float scale) {
    int i = blockIdx.x * blockDim.x + threadIdx.x;
    int cols = 1 << log2cols;
    if (i >= rows * cols) return;
    int r = i >> log2cols;
    int c = i & (cols - 1);
    out[c * rows + r] = (_Float16)(in[i] * scale);
}

// ---------------- phase 1: x_proj = inputs @ W_xh + b_h ----------------
// A [M,K] fp16 row-major, BT [N,K] fp16 (W_xh^T, x256), C [M,N] fp32.
// Block = 256 thr (4 waves, 2x2), block tile 128x128, wave tile 64x64 (4x4 MFMA 16x16x32).
__global__ __launch_bounds__(256) void gemm_xproj(
    const _Float16* __restrict__ A,
    const _Float16* __restrict__ BT,
    const float* __restrict__ bias,
    float* __restrict__ C,
    int M, int N, int K)
{
    int wave = threadIdx.x >> 6;
    int lane = threadIdx.x & 63;
    int q = lane >> 4;          // quad: k = q*8 + j for A/B fragments
    int r = lane & 15;          // row (A) / col (B) within 16
    int m0 = blockIdx.x * 128 + (wave >> 1) * 64;
    int n0 = blockIdx.y * 128 + (wave & 1) * 64;

    f32x4 acc[4][4] = {};
    for (int k = 0; k < K; k += 32) {
        int kk = k + q * 8;
        f16x8 a[4], b[4];
#pragma unroll
        for (int i = 0; i < 4; i++)
            a[i] = *(const f16x8*)(A + (size_t)(m0 + i * 16 + r) * K + kk);
#pragma unroll
        for (int j = 0; j < 4; j++)
            b[j] = *(const f16x8*)(BT + (size_t)(n0 + j * 16 + r) * K + kk);
#pragma unroll
        for (int i = 0; i < 4; i++)
#pragma unroll
            for (int j = 0; j < 4; j++)
                acc[i][j] = __builtin_amdgcn_mfma_f32_16x16x32_f16(a[i], b[j], acc[i][j], 0, 0, 0);
    }
#pragma unroll
    for (int i = 0; i < 4; i++)
#pragma unroll
        for (int j = 0; j < 4; j++)
#pragma unroll
            for (int reg = 0; reg < 4; reg++) {
                int row = m0 + i * 16 + q * 4 + reg;   // C/D: col=lane&15, row=(lane>>4)*4+reg
                int col = n0 + j * 16 + r;
                C[(size_t)row * N + col] = acc[i][j][reg] * W_INV_SCALE + bias[col];
            }
}

// ---------------- recurrent step: h = tanh(h_prev @ W_hh + x_proj_t) ----------------
// 64 blocks x 256 thr. Block owns 32 output columns (n0 = blockIdx.x*32), all 64 rows.
// K=2048 split 4 ways across waves (512 each); partials reduced through LDS.
__global__ __launch_bounds__(256) void rnn_step(
    const _Float16* __restrict__ h_prev,   // [B,H] fp16
    const _Float16* __restrict__ WT,       // [H,H] fp16 = W_hh^T x256 (WT[n][k])
    float* __restrict__ out_t,             // d_out + t*B*H; holds x_proj, overwritten with h
    _Float16* __restrict__ h_next,         // [B,H] fp16
    float* __restrict__ final_out)         // null unless last step
{
    __shared__ float lds[4 * 2048];
    int wave = threadIdx.x >> 6;
    int lane = threadIdx.x & 63;
    int q = lane >> 4, r = lane & 15;
    int n0 = blockIdx.x * 32;
    int kbase = wave * 512;

    f32x4 acc[4][2] = {};
    for (int k = kbase; k < kbase + 512; k += 32) {
        int kk = k + q * 8;
        f16x8 a[4], b[2];
#pragma unroll
        for (int i = 0; i < 4; i++)
            a[i] = *(const f16x8*)(h_prev + (size_t)(i * 16 + r) * H_SZ + kk);
#pragma unroll
        for (int j = 0; j < 2; j++)
            b[j] = *(const f16x8*)(WT + (size_t)(n0 + j * 16 + r) * H_SZ + kk);
#pragma unroll
        for (int i = 0; i < 4; i++)
#pragma unroll
            for (int j = 0; j < 2; j++)
                acc[i][j] = __builtin_amdgcn_mfma_f32_16x16x32_f16(a[i], b[j], acc[i][j], 0, 0, 0);
    }

    // stash partials: idx within wave = ((i*2+j)*4+reg)*64 + lane
#pragma unroll
    for (int i = 0; i < 4; i++)
#pragma unroll
        for (int j = 0; j < 2; j++)
#pragma unroll
            for (int reg = 0; reg < 4; reg++)
                lds[wave * 2048 + ((i * 2 + j) * 4 + reg) * 64 + lane] = acc[i][j][reg];
    __syncthreads();

    // reduce 4 K-partials, add x_proj, tanh, store
#pragma unroll
    for (int it = 0; it < 8; it++) {
        int idx = it * 256 + threadIdx.x;
        float s = lds[idx] + lds[2048 + idx] + lds[4096 + idx] + lds[6144 + idx];
        int lane_d = idx & 63;
        int reg = (idx >> 6) & 3;
        int j = (idx >> 8) & 1;
        int i = (idx >> 9) & 3;
        int row = i * 16 + (lane_d >> 4) * 4 + reg;      // batch index
        int col = n0 + j * 16 + (lane_d & 15);           // hidden index
        size_t o = (size_t)row * H_SZ + col;
        float v = tanhf(s * W_INV_SCALE + out_t[o]);
        out_t[o] = v;
        h_next[o] = (_Float16)v;
        if (final_out) final_out[o] = v;
    }
}

// ---------------- launcher ----------------

extern "C" void kernel_launch(void* const* d_in, const int* in_sizes, int n_in,
                              void* d_out, int out_size, void* d_ws, size_t ws_size,
                              hipStream_t stream) {
    const float* inputs = (const float*)d_in[0];   // [T,B,D]
    const float* state  = (const float*)d_in[1];   // [B,H]
    const float* W_xh   = (const float*)d_in[2];   // [D,H]
    const float* W_hh   = (const float*)d_in[3];   // [H,H]
    const float* b_h    = (const float*)d_in[4];   // [H]
    float* out = (float*)d_out;

    // workspace layout (fp16 buffers)
    const size_t OFF_IN   = 0;                                     // T*B*D fp16
    const size_t OFF_WXT  = OFF_IN  + (size_t)T_STEPS*B_SZ*D_SZ*2; // [H,D] fp16
    const size_t OFF_WHT  = OFF_WXT + (size_t)H_SZ*D_SZ*2;         // [H,H] fp16
    const size_t OFF_H0   = OFF_WHT + (size_t)H_SZ*H_SZ*2;         // [B,H] fp16
    const size_t OFF_H1   = OFF_H0  + (size_t)B_SZ*H_SZ*2;
    const size_t NEED     = OFF_H1  + (size_t)B_SZ*H_SZ*2;
    if (ws_size < NEED) return;  // insufficient scratch

    char* ws = (char*)d_ws;
    _Float16* inputs_f16 = (_Float16*)(ws + OFF_IN);
    _Float16* WxT        = (_Float16*)(ws + OFF_WXT);
    _Float16* WhT        = (_Float16*)(ws + OFF_WHT);
    _Float16* hbuf0      = (_Float16*)(ws + OFF_H0);
    _Float16* hbuf1      = (_Float16*)(ws + OFF_H1);

    const int n_in_el = T_STEPS * B_SZ * D_SZ;   // 16,777,216
    cvt_f32_f16<<<(n_in_el + 255) / 256, 256, 0, stream>>>(inputs, inputs_f16, n_in_el, 1.0f);
    transpose_to_f16<<<(D_SZ * H_SZ + 255) / 256, 256, 0, stream>>>(W_xh, WxT, D_SZ, 11, W_SCALE);
    transpose_to_f16<<<(H_SZ * H_SZ + 255) / 256, 256, 0, stream>>>(W_hh, WhT, H_SZ, 11, W_SCALE);
    cvt_f32_f16<<<(B_SZ * H_SZ + 255) / 256, 256, 0, stream>>>(state, hbuf0, B_SZ * H_SZ, 1.0f);

    // phase 1: x_proj -> d_out[0 : T*B*H]
    dim3 g1((T_STEPS * B_SZ) / 128, H_SZ / 128);
    gemm_xproj<<<g1, 256, 0, stream>>>(inputs_f16, WxT, b_h, out,
                                       T_STEPS * B_SZ, H_SZ, D_SZ);

    // phase 2: 256 dependent steps (kernel boundary = global barrier)
    float* final_out = out + (size_t)T_STEPS * B_SZ * H_SZ;
    for (int t = 0; t < T_STEPS; t++) {
        _Float16* hp = (t & 1) ? hbuf1 : hbuf0;
        _Float16* hn = (t & 1) ? hbuf0 : hbuf1;
        float* fo = (t == T_STEPS - 1) ? final_out : nullptr;
        rnn_step<<<64, 256, 0, stream>>>(hp, WhT, out + (size_t)t * B_SZ * H_SZ, hn, fo);
    }
}